// Round 4
// baseline (470.779 us; speedup 1.0000x reference)
//
#include <hip/hip_runtime.h>
#include <hip/hip_bf16.h>

typedef __attribute__((ext_vector_type(8))) __bf16 bf16x8;
typedef __attribute__((ext_vector_type(4))) float f32x4;

#define AS1 __attribute__((address_space(1)))
#define AS3 __attribute__((address_space(3)))

// ---------------- CSR build ----------------

__global__ void hist_kernel(const int* __restrict__ row, int* __restrict__ cnt, int e) {
  int i = blockIdx.x * 256 + threadIdx.x;
  if (i < e) atomicAdd(&cnt[row[i]], 1);
}

// fused scan: one block, 1024 threads, each owns a contiguous chunk
__global__ __launch_bounds__(1024) void scan_kernel(
    const int* __restrict__ cnt, int* __restrict__ off, int* __restrict__ cursor, int n, int e)
{
  __shared__ int sh[1024];
  const int tid = threadIdx.x;
  const int chunk = (n + 1023) >> 10;
  const int s0 = tid * chunk;
  const int s1 = (s0 + chunk < n) ? s0 + chunk : n;
  int sum = 0;
  for (int i = s0; i < s1; i++) sum += cnt[i];
  sh[tid] = sum;
  __syncthreads();
  for (int d = 1; d < 1024; d <<= 1) {
    int t = (tid >= d) ? sh[tid - d] : 0;
    __syncthreads();
    sh[tid] += t;
    __syncthreads();
  }
  int run = (tid > 0) ? sh[tid - 1] : 0;
  for (int i = s0; i < s1; i++) {
    int c = cnt[i];
    off[i] = run; cursor[i] = run; run += c;
  }
  if (tid == 0) off[n] = e;
}

__global__ void scatter_kernel(const int* __restrict__ row, const int* __restrict__ col,
                               int* __restrict__ cursor, int* __restrict__ scol, int e) {
  int i = blockIdx.x * 256 + threadIdx.x;
  if (i < e) { int r = row[i]; int pos = atomicAdd(&cursor[r], 1); scol[pos] = col[i]; }
}

// ---------------- W prep: Wt[c][k] = bf16(W[k][c]), c in [0,640) = q|kv|vec ----------------

__global__ void wprep_kernel(const float* __restrict__ Wq, const float* __restrict__ Wkv,
                             const float* __restrict__ Wvec, __bf16* __restrict__ Wt) {
  int idx = blockIdx.x * 256 + threadIdx.x;      // 640*128 = 81920
  int c = idx >> 7, k = idx & 127;
  float w;
  if (c < 128)      w = Wq[k * 128 + c];
  else if (c < 512) w = Wkv[k * 384 + (c - 128)];
  else              w = Wvec[k * 128 + (c - 512)];
  Wt[idx] = (__bf16)w;
}

// ---------------- GEMM1 (MFMA): 64 rows x 128 cols per block; A direct-loaded ----------------
// blockIdx.y: 0 -> q (f32), 1 -> k (bf16), 2 -> v_s (bf16), 3 -> P = v_v*v (bf16 x3)

__global__ __launch_bounds__(256) void gemm1_mfma(
    const float* __restrict__ s, const __bf16* __restrict__ Wtg,
    const float* __restrict__ bq, const float* __restrict__ bkv,
    const float* __restrict__ v,
    float* __restrict__ q_out, __bf16* __restrict__ nodebuf, int n)
{
  __shared__ __bf16 sB[128 * 136];    // W^T chunk [col][k], padded stride
  const int tid = threadIdx.x;
  const int y = blockIdx.y;
  const int n0 = blockIdx.x * 64;

  {  // stage B chunk
    int row = tid >> 1, half = tid & 1;
    const __bf16* src = &Wtg[(size_t)(y * 128 + row) * 128 + half * 64];
    #pragma unroll
    for (int i = 0; i < 8; i++)
      *(bf16x8*)&sB[row * 136 + half * 64 + i * 8] = *(const bf16x8*)&src[i * 8];
  }

  const int wave = tid >> 6, lane = tid & 63;
  const int lr = lane & 15, lg = lane >> 4;
  const int grow = n0 + wave * 16 + lr;

  bf16x8 a[4];
  if (grow < n) {
    #pragma unroll
    for (int ks = 0; ks < 4; ks++) {
      float4 f0 = *(const float4*)&s[(size_t)grow * 128 + ks * 32 + lg * 8];
      float4 f1 = *(const float4*)&s[(size_t)grow * 128 + ks * 32 + lg * 8 + 4];
      bf16x8 pk;
      pk[0] = (__bf16)f0.x; pk[1] = (__bf16)f0.y; pk[2] = (__bf16)f0.z; pk[3] = (__bf16)f0.w;
      pk[4] = (__bf16)f1.x; pk[5] = (__bf16)f1.y; pk[6] = (__bf16)f1.z; pk[7] = (__bf16)f1.w;
      a[ks] = pk;
    }
  } else {
    #pragma unroll
    for (int ks = 0; ks < 4; ks++) a[ks] = bf16x8{0,0,0,0,0,0,0,0};
  }

  __syncthreads();

  f32x4 acc[8];
  #pragma unroll
  for (int cf = 0; cf < 8; cf++) {
    f32x4 c = {0.f, 0.f, 0.f, 0.f};
    #pragma unroll
    for (int ks = 0; ks < 4; ks++) {
      bf16x8 b = *(const bf16x8*)&sB[(cf * 16 + lr) * 136 + ks * 32 + lg * 8];
      c = __builtin_amdgcn_mfma_f32_16x16x32_bf16(a[ks], b, c, 0, 0, 0);
    }
    acc[cf] = c;
  }

  // epilogue: D row = (lane>>4)*4 + r, col = lane&15
  #pragma unroll
  for (int cf = 0; cf < 8; cf++) {
    int cl = cf * 16 + lr;
    #pragma unroll
    for (int r = 0; r < 4; r++) {
      int gn = n0 + wave * 16 + lg * 4 + r;
      if (gn >= n) continue;
      float val = acc[cf][r];
      if (y == 0) {
        q_out[(size_t)gn * 128 + cl] = val + bq[cl];
      } else if (y == 1) {
        nodebuf[(size_t)gn * 640 + cl] = (__bf16)(val + bkv[cl]);
      } else if (y == 2) {
        nodebuf[(size_t)gn * 640 + 128 + cl] = (__bf16)(val + bkv[128 + cl]);
      } else {
        float vv = val + bkv[256 + cl];
        #pragma unroll
        for (int j3 = 0; j3 < 3; j3++) {
          float pv = vv * v[((size_t)gn * 3 + j3) * 128 + cl];
          nodebuf[(size_t)gn * 640 + 256 + j3 * 128 + cl] = (__bf16)pv;
        }
      }
    }
  }
}

// ---------------- Aggregation: one wave/node, 4-slot LDS-DMA ring, counted vmcnt ----------------

__device__ inline float2 bf2f(unsigned u) {
  float2 r;
  r.x = __uint_as_float((u & 0xffffu) << 16);
  r.y = __uint_as_float(u & 0xffff0000u);
  return r;
}

__device__ __forceinline__ void issue_edge(const char* nb, int c, char* slotbase, int lane) {
  const char* g = nb + (size_t)c * 1280;
  __builtin_amdgcn_global_load_lds((AS1 void*)const_cast<char*>(g + (size_t)lane * 16),
                                   (AS3 void*)slotbase, 16, 0, 0);
  __builtin_amdgcn_global_load_lds((AS1 void*)const_cast<char*>(g + 1024 + (size_t)lane * 4),
                                   (AS3 void*)(slotbase + 1024), 4, 0, 0);
}

__device__ __forceinline__ void edge_math(unsigned ku, unsigned vs, unsigned p0,
                                          unsigned p1, unsigned p2,
                                          float qx, float qy,
                                          float2& accs, float2& av0, float2& av1, float2& av2) {
  float2 k2 = bf2f(ku);
  float d = qx * k2.x + qy * k2.y;
  d += __shfl_xor(d, 32); d += __shfl_xor(d, 16); d += __shfl_xor(d, 8);
  d += __shfl_xor(d, 4);  d += __shfl_xor(d, 2);  d += __shfl_xor(d, 1);
  float2 t;
  t = bf2f(vs); accs.x += d * t.x; accs.y += d * t.y;
  t = bf2f(p0); av0.x  += d * t.x; av0.y  += d * t.y;
  t = bf2f(p1); av1.x  += d * t.x; av1.y  += d * t.y;
  t = bf2f(p2); av2.x  += d * t.x; av2.y  += d * t.y;
}

__device__ __forceinline__ void edge_compute_ptr(const unsigned* sl, int lane,
                                                 float qx, float qy,
                                                 float2& accs, float2& av0, float2& av1, float2& av2) {
  unsigned ku = sl[lane];
  unsigned vs = sl[64 + lane];
  unsigned p0 = sl[128 + lane];
  unsigned p1 = sl[192 + lane];
  unsigned p2 = sl[256 + lane];
  edge_math(ku, vs, p0, p1, p2, qx, qy, accs, av0, av1, av2);
}

__global__ __launch_bounds__(256) void agg_kernel(
    const int* __restrict__ off, const int* __restrict__ scol,
    const float* __restrict__ q, const char* __restrict__ nodebuf,
    const float* __restrict__ s, float* __restrict__ s_out, float* __restrict__ aggv, int n)
{
  __shared__ char lds[4][4 * 1280];
  const int wid = threadIdx.x >> 6;
  const int lane = threadIdx.x & 63;
  const int nid = blockIdx.x * 4 + wid;
  if (nid >= n) return;
  char* myl = lds[wid];
  const char* nb = nodebuf;

  const int beg = off[nid], end = off[nid + 1];
  const int deg = end - beg;
  const int deg2 = deg < 64 ? deg : 64;

  int myc = 0;
  if (lane < deg2) myc = scol[beg + lane];

  float2 qa   = *(const float2*)&q[(size_t)nid * 128 + lane * 2];
  float2 accs = *(const float2*)&s[(size_t)nid * 128 + lane * 2];
  float2 av0{0.f, 0.f}, av1{0.f, 0.f}, av2{0.f, 0.f};

  // pin initial loads resolved here so no compiler vmcnt waits appear inside the loop
  asm volatile("" : "+v"(qa.x), "+v"(qa.y), "+v"(accs.x), "+v"(accs.y), "+v"(myc));
  float qx = qa.x, qy = qa.y;

  const int I0 = deg2 < 4 ? deg2 : 4;
  for (int j = 0; j < I0; ++j)
    issue_edge(nb, __shfl(myc, j), myl + (j & 3) * 1280, lane);

  int e = 0;
  for (int issued = I0; issued < deg2; ++e, ++issued) {
    asm volatile("s_waitcnt vmcnt(6)" ::: "memory");   // oldest edge's 2 ops complete
    const unsigned* sl = (const unsigned*)(myl + (e & 3) * 1280);
    unsigned ku = sl[lane];
    unsigned vs = sl[64 + lane];
    unsigned p0 = sl[128 + lane];
    unsigned p1 = sl[192 + lane];
    unsigned p2 = sl[256 + lane];
    asm volatile("s_waitcnt lgkmcnt(0)" ::: "memory"); // values in regs before slot refill
    issue_edge(nb, __shfl(myc, issued), myl + (e & 3) * 1280, lane);
    edge_math(ku, vs, p0, p1, p2, qx, qy, accs, av0, av1, av2);
  }

  // drain: rem = deg2 - e edges outstanding, literal vmcnt per step
  {
    const int rem = deg2 - e;
    #pragma unroll
    for (int kk = 3; kk >= 0; --kk) {
      if (kk < rem) {
        asm volatile("s_waitcnt vmcnt(%0)" :: "n"(kk * 2) : "memory");
        int j = deg2 - 1 - kk;
        const unsigned* sl = (const unsigned*)(myl + (j & 3) * 1280);
        edge_compute_ptr(sl, lane, qx, qy, accs, av0, av1, av2);
      }
    }
  }

  // astronomically rare fallback (deg > 64): direct global gather
  for (int j = 64; j < deg; ++j) {
    int c = scol[beg + j];
    const unsigned* b = (const unsigned*)(nb + (size_t)c * 1280);
    edge_compute_ptr(b, lane, qx, qy, accs, av0, av1, av2);
  }

  *(float2*)&s_out[(size_t)nid * 128 + lane * 2] = accs;
  *(float2*)&aggv[((size_t)nid * 3 + 0) * 128 + lane * 2] = av0;
  *(float2*)&aggv[((size_t)nid * 3 + 1) * 128 + lane * 2] = av1;
  *(float2*)&aggv[((size_t)nid * 3 + 2) * 128 + lane * 2] = av2;
}

// ---------------- GEMM2 (MFMA): vout = v + aggv @ Wvec + bvec, in-place on aggv rows ----------------

__global__ __launch_bounds__(256) void gemm2_mfma(
    const __bf16* __restrict__ Wtg,   // use rows 512..639 (Wvec^T)
    const float* __restrict__ bvec, const float* __restrict__ v,
    float* __restrict__ vout, int rows)
{
  __shared__ __bf16 sB[128 * 136];
  const int tid = threadIdx.x;
  const int r0 = blockIdx.x * 64;

  {  // stage Wvec^T
    int row = tid >> 1, half = tid & 1;
    const __bf16* src = &Wtg[(size_t)(512 + row) * 128 + half * 64];
    #pragma unroll
    for (int i = 0; i < 8; i++)
      *(bf16x8*)&sB[row * 136 + half * 64 + i * 8] = *(const bf16x8*)&src[i * 8];
  }

  const int wave = tid >> 6, lane = tid & 63;
  const int lr = lane & 15, lg = lane >> 4;
  const int grow = r0 + wave * 16 + lr;

  bf16x8 a[4];
  if (grow < rows) {
    #pragma unroll
    for (int ks = 0; ks < 4; ks++) {
      float4 f0 = *(const float4*)&vout[(size_t)grow * 128 + ks * 32 + lg * 8];
      float4 f1 = *(const float4*)&vout[(size_t)grow * 128 + ks * 32 + lg * 8 + 4];
      bf16x8 pk;
      pk[0] = (__bf16)f0.x; pk[1] = (__bf16)f0.y; pk[2] = (__bf16)f0.z; pk[3] = (__bf16)f0.w;
      pk[4] = (__bf16)f1.x; pk[5] = (__bf16)f1.y; pk[6] = (__bf16)f1.z; pk[7] = (__bf16)f1.w;
      a[ks] = pk;
    }
  } else {
    #pragma unroll
    for (int ks = 0; ks < 4; ks++) a[ks] = bf16x8{0,0,0,0,0,0,0,0};
  }

  __syncthreads();

  f32x4 acc[8];
  #pragma unroll
  for (int cf = 0; cf < 8; cf++) {
    f32x4 c = {0.f, 0.f, 0.f, 0.f};
    #pragma unroll
    for (int ks = 0; ks < 4; ks++) {
      bf16x8 b = *(const bf16x8*)&sB[(cf * 16 + lr) * 136 + ks * 32 + lg * 8];
      c = __builtin_amdgcn_mfma_f32_16x16x32_bf16(a[ks], b, c, 0, 0, 0);
    }
    acc[cf] = c;
  }

  #pragma unroll
  for (int cf = 0; cf < 8; cf++) {
    int cl = cf * 16 + lr;
    #pragma unroll
    for (int r = 0; r < 4; r++) {
      int gr = r0 + wave * 16 + lg * 4 + r;
      if (gr >= rows) continue;
      vout[(size_t)gr * 128 + cl] = acc[cf][r] + v[(size_t)gr * 128 + cl] + bvec[cl];
    }
  }
}

// ---------------- launch ----------------

extern "C" void kernel_launch(void* const* d_in, const int* in_sizes, int n_in,
                              void* d_out, int out_size, void* d_ws, size_t ws_size,
                              hipStream_t stream)
{
  const float* s    = (const float*)d_in[0];
  const float* v    = (const float*)d_in[1];
  const int*   ei   = (const int*)d_in[2];
  const float* Wq   = (const float*)d_in[3];
  const float* bq   = (const float*)d_in[4];
  const float* Wkv  = (const float*)d_in[5];
  const float* bkv  = (const float*)d_in[6];
  const float* Wvec = (const float*)d_in[7];
  const float* bvec = (const float*)d_in[8];

  const int N = in_sizes[0] / 128;
  const int E = in_sizes[2] / 2;
  const int* row = ei;
  const int* col = ei + E;

  char* ws = (char*)d_ws;
  size_t o = 0;
  auto alloc = [&](size_t bytes) -> char* {
    char* p = ws + o;
    o = (o + bytes + 255) & ~(size_t)255;
    return p;
  };
  int* off    = (int*)alloc((size_t)(N + 1) * 4);
  int* cursor = (int*)alloc((size_t)N * 4);       // doubles as histogram counts
  int* scol   = (int*)alloc((size_t)E * 4);
  float* qbuf = (float*)alloc((size_t)N * 128 * 4);
  __bf16* nodebuf = (__bf16*)alloc((size_t)N * 640 * 2);
  __bf16* Wt  = (__bf16*)alloc((size_t)640 * 128 * 2);

  float* s_out = (float*)d_out;
  float* aggv  = (float*)d_out + (size_t)N * 128;

  // CSR build
  hipMemsetAsync(cursor, 0, (size_t)N * 4, stream);
  hist_kernel<<<(E + 255) / 256, 256, 0, stream>>>(row, cursor, E);
  scan_kernel<<<1, 1024, 0, stream>>>(cursor, off, cursor, N, E);
  scatter_kernel<<<(E + 255) / 256, 256, 0, stream>>>(row, col, cursor, scol, E);

  // weight prep + node features (MFMA)
  wprep_kernel<<<320, 256, 0, stream>>>(Wq, Wkv, Wvec, Wt);
  dim3 g1((N + 63) / 64, 4);
  gemm1_mfma<<<g1, 256, 0, stream>>>(s, Wt, bq, bkv, v, qbuf, nodebuf, N);

  // edge aggregation (one wave per node, LDS-DMA pipeline)
  agg_kernel<<<(N + 3) / 4, 256, 0, stream>>>(off, scol, qbuf, (const char*)nodebuf,
                                              s, s_out, aggv, N);

  // v_out GEMM (MFMA, in-place on d_out v region)
  gemm2_mfma<<<(3 * N + 63) / 64, 256, 0, stream>>>(Wt, bvec, v, aggv, 3 * N);
}